// Round 13
// baseline (188.711 us; speedup 1.0000x reference)
//
#include <hip/hip_runtime.h>
#include <math.h>

#define HEADS 3
#define FILT 16
#define HF 48   // HEADS*FILT
#define VF 11

#define NBGP 2048          // k_gp blocks (x4 waves = 8192 waves)
#define NBINMAX 512        // bins of 256 dst each; N<=131072
#define CAP0 4096          // slack per bin, branch 0 (E0=400K, mean ~1k/bin)
#define CAP1 8192          // slack per bin, branch 1 (E1=1.6M, mean ~4k/bin)
#define SCCH 8192          // edges per k_binscatter block

typedef unsigned int uint;
typedef unsigned short ushort;

__device__ inline uint f2bf(float x) {        // RNE f32->bf16 bits
    uint u = __float_as_uint(x);
    return (u + 0x7FFFu + ((u >> 16) & 1u)) >> 16;
}

__device__ inline float tanh_fast(float s) {
    const float sc = fminf(fmaxf(s, -15.f), 15.f);
    const float t = __expf(2.f * sc);
    return (t - 1.f) / (t + 1.f);
}

// ws layout (floats), Nl = N, nbin=(N+255)>>8:
//   h0 bf16[pad 128B rows] @0 (32N)   h1 @32N (32N)
//   es0[4N]@64N ed0[4N]@68N es1[4N]@72N ed1[4N]@76N
//   ms0 int2[N] @80N   ms1 int2[N] @82N     (cnt, bucket-end)
//   binfill[2*NBINMAX] @84N                  (ints)
//   pk0[nbin*CAP0] pk1[nbin*CAP1] bk0[nbin*CAP0] bk1[nbin*CAP1] after
//   gpart[NBGP*6] after
//   pd (branch-0 partial dots, 6N) ALIASES pk0 (dead after k_binbucket)

// -------------------- K1: per-node transform + init --------------------
__global__ __launch_bounds__(256) void k_nodes(
    const float* __restrict__ nf,
    const float* __restrict__ W_int, const float* __restrict__ as_int, const float* __restrict__ ad_int,
    const float* __restrict__ W_nh,  const float* __restrict__ as_nh,  const float* __restrict__ ad_nh,
    float* __restrict__ ws, int* __restrict__ binfill, int N)
{
    __shared__ float sW0[VF*HF], sW1[VF*HF];
    __shared__ float sa[4][HF];
    __shared__ float sF[64*VF];
    __shared__ uint  sH[64*32];
    const int t = threadIdx.x;
    for (int i = t; i < VF*HF; i += 256) { sW0[i] = W_int[i]; sW1[i] = W_nh[i]; }
    if (t < HF) { sa[0][t] = as_int[t]; sa[1][t] = ad_int[t]; sa[2][t] = as_nh[t]; sa[3][t] = ad_nh[t]; }

    const long Nl = N;
    const long B0 = (long)blockIdx.x * 64;
    {
        const long idx = (long)blockIdx.x * 256 + t;
        if (idx < 2*NBINMAX) binfill[idx] = 0;
    }
    // stage node features (coalesced)
    for (int i = t; i < 64*VF; i += 256) {
        const long g = B0*VF + i;
        sF[i] = (g < Nl*VF) ? nf[g] : 0.f;
    }
    __syncthreads();

    const int nl = t >> 2;       // local node 0..63
    const int q  = t & 3;        // feature quarter
    const long n = B0 + nl;
    const bool valid = n < Nl;

    float f[VF];
    #pragma unroll
    for (int v = 0; v < VF; v++) f[v] = sF[nl*VF + v];

    for (int b = 0; b < 2; b++) {
        if (b == 1) __syncthreads();   // protect sH reuse
        const float* W = b ? sW1 : sW0;
        float acc[12];
        #pragma unroll
        for (int j = 0; j < 12; j++) acc[j] = 0.f;
        #pragma unroll
        for (int v = 0; v < VF; v++) {
            const float fv = f[v];
            #pragma unroll
            for (int j = 0; j < 12; j++)
                acc[j] = fmaf(fv, W[v*HF + q*12 + j], acc[j]);
        }
        // stage bf16 pairs (6 dwords) + this thread's share of the pad
        #pragma unroll
        for (int i = 0; i < 6; i++)
            sH[nl*32 + q*6 + i] = f2bf(acc[2*i]) | (f2bf(acc[2*i+1]) << 16);
        sH[nl*32 + 24 + 2*q + 0] = 0u;
        sH[nl*32 + 24 + 2*q + 1] = 0u;

        // partial head-dots over this thread's 12 feats (predicated by head)
        float s0=0.f,s1=0.f,s2=0.f,d0=0.f,d1=0.f,d2=0.f;
        #pragma unroll
        for (int j = 0; j < 12; j++) {
            const int fg = q*12 + j;
            const int hd = fg >> 4;
            const float ps = acc[j] * sa[2*b + 0][fg];
            const float pd = acc[j] * sa[2*b + 1][fg];
            s0 += (hd == 0) ? ps : 0.f;  d0 += (hd == 0) ? pd : 0.f;
            s1 += (hd == 1) ? ps : 0.f;  d1 += (hd == 1) ? pd : 0.f;
            s2 += (hd == 2) ? ps : 0.f;  d2 += (hd == 2) ? pd : 0.f;
        }
        s0 += __shfl_xor(s0,1); s0 += __shfl_xor(s0,2);
        s1 += __shfl_xor(s1,1); s1 += __shfl_xor(s1,2);
        s2 += __shfl_xor(s2,1); s2 += __shfl_xor(s2,2);
        d0 += __shfl_xor(d0,1); d0 += __shfl_xor(d0,2);
        d1 += __shfl_xor(d1,1); d1 += __shfl_xor(d1,2);
        d2 += __shfl_xor(d2,1); d2 += __shfl_xor(d2,2);
        if (valid && q == 0) {
            float* ES = ws + 64*Nl + (b ? 8*Nl : 0);
            float* ED = ES + 4*Nl;
            ((float4*)ES)[n] = make_float4(s0, s1, s2, 0.f);
            ((float4*)ED)[n] = make_float4(d0, d1, d2, 0.f);
        }
        __syncthreads();
        // coalesced H write: 2048 dwords per block, 4 full lines per instr
        uint* Hg = (uint*)(ws + (b ? 32*Nl : 0));
        for (int i = t; i < 64*32; i += 256) {
            const long node = B0 + (i >> 5);
            if (node < Nl) Hg[B0*32 + i] = sH[i];
        }
    }
}

// -------------------- K2: multi-split edges into slack bins --------------------
__global__ __launch_bounds__(256) void k_binscatter(
    const int* __restrict__ e0, int E0, int nb0,
    const int* __restrict__ e1, int E1,
    int* __restrict__ binfill, uint* __restrict__ pk0, uint* __restrict__ pk1)
{
    __shared__ int lh[NBINMAX], lb[NBINMAX];
    const int b = blockIdx.x;
    const int* e; long E; int* bf; uint* pk; int bb, cap;
    if (b < nb0) { e = e0; E = E0; bf = binfill;           pk = pk0; bb = b;       cap = CAP0; }
    else         { e = e1; E = E1; bf = binfill + NBINMAX; pk = pk1; bb = b - nb0; cap = CAP1; }
    for (int i = threadIdx.x; i < NBINMAX; i += 256) lh[i] = 0;
    __syncthreads();
    const int t = threadIdx.x;
    const long base = (long)bb * SCCH;
    // phase 1: count
    #pragma unroll 4
    for (int k = 0; k < SCCH/256; k++) {
        const long i = base + (long)k*256 + t;
        if (i < E) atomicAdd(&lh[e[E + i] >> 8], 1);
    }
    __syncthreads();
    // phase 2: reserve slack space per bin; reset local counters
    for (int i = t; i < NBINMAX; i += 256) {
        const int c = lh[i];
        lb[i] = c ? atomicAdd(&bf[i], c) : 0;
        lh[i] = 0;
    }
    __syncthreads();
    // phase 3: scatter packed (dstl<<17 | src)
    #pragma unroll 4
    for (int k = 0; k < SCCH/256; k++) {
        const long i = base + (long)k*256 + t;
        if (i < E) {
            const int s = e[i];
            const int d = e[E + i];
            const int bin = d >> 8;
            const int off = atomicAdd(&lh[bin], 1);
            pk[(long)bin*cap + lb[bin] + off] = ((uint)(d & 255) << 17) | (uint)s;
        }
    }
}

// -------------------- K3: per-bin bucket build (LDS counts + local scatter) -----
__global__ __launch_bounds__(256) void k_binbucket(
    const uint* __restrict__ pk0, const uint* __restrict__ pk1,
    const int* __restrict__ binfill, int nbin,
    int2* __restrict__ ms0, int* __restrict__ bk0,
    int2* __restrict__ ms1, int* __restrict__ bk1, int N)
{
    __shared__ int nc[256], ns[256], wsum[4];
    const int b = blockIdx.x;
    const int br = (b < nbin) ? 0 : 1;
    const int bin = b - br*nbin;
    const uint* pk = br ? pk1 : pk0;
    const int cap  = br ? CAP1 : CAP0;
    int2* ms = br ? ms1 : ms0;
    int* bk  = br ? bk1 : bk0;
    const long pbase = (long)bin * cap;
    const int m = binfill[br*NBINMAX + bin];
    const int t = threadIdx.x, lane = t & 63, wid = t >> 6;

    nc[t] = 0;
    __syncthreads();
    for (int i = t; i < m; i += 256)
        atomicAdd(&nc[(pk[pbase + i] >> 17) & 255], 1);
    __syncthreads();
    // exclusive scan of nc[256] -> ns
    const int v = nc[t];
    int x = v;
    #pragma unroll
    for (int d = 1; d < 64; d <<= 1) { const int u = __shfl_up(x, d); if (lane >= d) x += u; }
    if (lane == 63) wsum[wid] = x;
    __syncthreads();
    int wb = 0;
    #pragma unroll
    for (int w = 0; w < 4; w++) if (w < wid) wb += wsum[w];
    ns[t] = wb + x - v;
    const int n = bin*256 + t;
    if (n < N) ms[n] = make_int2(v, (int)pbase + ns[t] + v);   // (cnt, bucket END)
    nc[t] = 0;
    __syncthreads();
    for (int i = t; i < m; i += 256) {
        const uint p = pk[pbase + i];
        const int dl = (p >> 17) & 255;
        const int off = atomicAdd(&nc[dl], 1);
        bk[pbase + ns[dl] + off] = (int)(p & 0x1FFFFu);
    }
}

// -------------------- K4: gather-reduce + fused pooling --------------------
// Branch-phased: outer loop b; 4 chains = 4 DIFFERENT nodes, same branch
// (halves the live H footprint -> higher L2 hit rate; ILP preserved).
// Pooling is separable across branches: phase 0 stores 6 partial dots per
// node in pd[]; phase 1 adds its partials and finalizes exp(tanh(s))*y.
__global__ __launch_bounds__(256) void k_gp(
    const uint* __restrict__ H0, const uint* __restrict__ H1,
    const float* __restrict__ ES0, const float4* __restrict__ ED0,
    const float* __restrict__ ES1, const float4* __restrict__ ED1,
    const int2* __restrict__ ms0, const int* __restrict__ bk0,
    const int2* __restrict__ ms1, const int* __restrict__ bk1,
    const float* __restrict__ att_w, const float* __restrict__ dense_w,
    float* __restrict__ pd, float* __restrict__ gpart, int N)
{
    __shared__ int   sIdx[4][4*64];
    __shared__ float sP[4][4*192];
    const int t = threadIdx.x, lane = t & 63, wid = t >> 6;
    const int half = lane >> 5;          // 0: edge j, 1: edge j+1
    const int hl = lane & 31;            // dword within 128B row
    const int hcc = (hl >> 3) < 3 ? (hl >> 3) : 2;

    // pooling coefficients: half 0 -> score dots, half 1 -> dense dots
    float cL0[3]={0,0,0}, cH0[3]={0,0,0}, cL1[3]={0,0,0}, cH1[3]={0,0,0};
    if (hl < 24) {
        const int f0 = 2*hl, f1 = f0 + 1;
        #pragma unroll
        for (int k = 0; k < 3; k++) {
            if (half == 0) {
                cL0[k] = att_w[f0*3 + k];        cH0[k] = att_w[f1*3 + k];
                cL1[k] = att_w[(HF+f0)*3 + k];   cH1[k] = att_w[(HF+f1)*3 + k];
            } else {
                cL0[k] = dense_w[k*96 + f0];     cH0[k] = dense_w[k*96 + f1];
                cL1[k] = dense_w[k*96 + HF+f0];  cH1[k] = dense_w[k*96 + HF+f1];
            }
        }
    }

    int* iw = sIdx[wid];
    float* pw = sP[wid];

    float acc6[6] = {0,0,0,0,0,0};
    const int gw = blockIdx.x*4 + wid;
    const int nw = NBGP*4;

    for (int b = 0; b < 2; b++) {
        const uint* H    = b ? H1  : H0;
        const float* ES  = b ? ES1 : ES0;
        const float4* ED = b ? ED1 : ED0;
        const int2* ms   = b ? ms1 : ms0;
        const int* bk    = b ? bk1 : bk0;
        const float cbL[3] = { b ? cL1[0] : cL0[0], b ? cL1[1] : cL0[1], b ? cL1[2] : cL0[2] };
        const float cbH[3] = { b ? cH1[0] : cH0[0], b ? cH1[1] : cH0[1], b ? cH1[2] : cH0[2] };

        for (int n = gw; n < N; n += 4*nw) {
            int nd[4]; bool val[4];
            #pragma unroll
            for (int T = 0; T < 4; T++) { nd[T] = n + T*nw; val[T] = nd[T] < N; }
            int deg[4], bas[4];
            #pragma unroll
            for (int T = 0; T < 4; T++) {
                const int2 m2 = val[T] ? ms[nd[T]] : make_int2(0, 0);
                deg[T] = m2.x; bas[T] = m2.y - m2.x;
            }
            const int mx = max(max(deg[0], deg[1]), max(deg[2], deg[3]));

            float xL[4], xH[4];

            if (mx <= 64) {
                // ---- phase A, 4 nodes interleaved ----
                float4 ev[4];
                #pragma unroll
                for (int T = 0; T < 4; T++) ev[T] = val[T] ? ED[nd[T]] : make_float4(0,0,0,0);
                int sv[4];
                #pragma unroll
                for (int T = 0; T < 4; T++) sv[T] = (lane < deg[T]) ? bk[bas[T] + lane] : 0;
                float4 es[4];
                #pragma unroll
                for (int T = 0; T < 4; T++) es[T] = ((const float4*)ES)[sv[T]];
                #pragma unroll
                for (int T = 0; T < 4; T++) {
                    float v0 = es[T].x + ev[T].x, v1 = es[T].y + ev[T].y, v2 = es[T].z + ev[T].z;
                    v0 = fmaxf(v0, 0.2f*v0);
                    v1 = fmaxf(v1, 0.2f*v1);
                    v2 = fmaxf(v2, 0.2f*v2);
                    const bool a = lane < deg[T];
                    const float p0 = a ? __expf(v0) : 0.f;
                    const float p1 = a ? __expf(v1) : 0.f;
                    const float p2 = a ? __expf(v2) : 0.f;
                    iw[T*64 + lane] = sv[T];
                    pw[T*192 + lane*3 + 0] = p0;
                    pw[T*192 + lane*3 + 1] = p1;
                    pw[T*192 + lane*3 + 2] = p2;
                }
                // ---- phase B: rounds of 8 edges, 4 nodes' loads issued together ----
                float accL[4] = {0,0,0,0}, accH[4] = {0,0,0,0}, den[4] = {0,0,0,0};
                const int R = (mx + 7) >> 3;
                for (int r = 0; r < R; r++) {
                    const int j0 = r*8;
                    uint w[4][4]; float q[4][4];
                    #pragma unroll
                    for (int T = 0; T < 4; T++) {
                        if (j0 < deg[T]) {
                            #pragma unroll
                            for (int u = 0; u < 4; u++) {
                                const int ei = j0 + 2*u + half;
                                q[T][u] = pw[T*192 + ei*3 + hcc];
                                w[T][u] = H[(long)iw[T*64 + ei]*32 + hl];
                            }
                        }
                    }
                    #pragma unroll
                    for (int T = 0; T < 4; T++) {
                        if (j0 < deg[T]) {
                            #pragma unroll
                            for (int u = 0; u < 4; u++) {
                                accL[T] = fmaf(q[T][u], __uint_as_float(w[T][u] << 16), accL[T]);
                                accH[T] = fmaf(q[T][u], __uint_as_float(w[T][u] & 0xFFFF0000u), accH[T]);
                                den[T] += q[T][u];
                            }
                        }
                    }
                }
                #pragma unroll
                for (int T = 0; T < 4; T++) {
                    accL[T] += __shfl_xor(accL[T], 32);
                    accH[T] += __shfl_xor(accH[T], 32);
                    den[T]  += __shfl_xor(den[T], 32);
                    const float dinv = 1.f / (den[T] + 1e-16f);
                    xL[T] = accL[T] * dinv;
                    xH[T] = accH[T] * dinv;
                }
            } else {
                // ---- slow path (deg > 64 somewhere): chunked per task ----
                #pragma unroll
                for (int T = 0; T < 4; T++) {
                    float accL = 0.f, accH = 0.f, dn = 0.f;
                    if (deg[T] > 0) {
                        const float4 edv = ED[nd[T]];
                        for (int e0 = 0; e0 < deg[T]; e0 += 64) {
                            int m = deg[T] - e0; if (m > 64) m = 64;
                            int srcv = 0; float p0 = 0.f, p1 = 0.f, p2 = 0.f;
                            if (lane < m) {
                                srcv = bk[bas[T] + e0 + lane];
                                const float4 esv = ((const float4*)ES)[srcv];
                                float v0 = esv.x + edv.x, v1 = esv.y + edv.y, v2 = esv.z + edv.z;
                                v0 = fmaxf(v0, 0.2f*v0);
                                v1 = fmaxf(v1, 0.2f*v1);
                                v2 = fmaxf(v2, 0.2f*v2);
                                p0 = __expf(v0); p1 = __expf(v1); p2 = __expf(v2);
                            }
                            iw[lane] = srcv;
                            pw[lane*3 + 0] = p0; pw[lane*3 + 1] = p1; pw[lane*3 + 2] = p2;
                            for (int j = 0; j < m; j += 2) {
                                const int ei = j + half;
                                const float qq = pw[ei*3 + hcc];
                                const uint wv = H[(long)iw[ei]*32 + hl];
                                accL = fmaf(qq, __uint_as_float(wv << 16), accL);
                                accH = fmaf(qq, __uint_as_float(wv & 0xFFFF0000u), accH);
                                dn += qq;
                            }
                        }
                    }
                    accL += __shfl_xor(accL, 32);
                    accH += __shfl_xor(accH, 32);
                    dn   += __shfl_xor(dn, 32);
                    const float dinv = 1.f / (dn + 1e-16f);
                    xL[T] = accL * dinv;
                    xH[T] = accH * dinv;
                }
            }

            // ---- pooling partials per node ----
            #pragma unroll
            for (int T = 0; T < 4; T++) {
                if (!val[T]) continue;
                float rr[3];
                #pragma unroll
                for (int k = 0; k < 3; k++)
                    rr[k] = xL[T]*cbL[k] + xH[T]*cbH[k];
                #pragma unroll
                for (int k = 0; k < 3; k++) {
                    #pragma unroll
                    for (int o = 1; o < 32; o <<= 1) rr[k] += __shfl_xor(rr[k], o);
                }
                if (b == 0) {
                    // lanes 0 (scores) and 32 (dense) store 3 partials each
                    if (hl == 0) {
                        const long n6 = (long)nd[T]*6 + (half ? 3 : 0);
                        pd[n6 + 0] = rr[0]; pd[n6 + 1] = rr[1]; pd[n6 + 2] = rr[2];
                    }
                } else {
                    float oo[3];
                    #pragma unroll
                    for (int k = 0; k < 3; k++) oo[k] = __shfl_xor(rr[k], 32);
                    if (lane == 0) {
                        const long n6 = (long)nd[T]*6;
                        #pragma unroll
                        for (int k = 0; k < 3; k++) {
                            const float s = pd[n6 + k] + rr[k];
                            const float y = pd[n6 + 3 + k] + oo[k];
                            const float e = __expf(tanh_fast(s));
                            acc6[k]   += e;
                            acc6[3+k] += e * y;
                        }
                    }
                }
            }
        }
    }

    __shared__ float red[4][6];
    if (lane == 0) {
        #pragma unroll
        for (int k = 0; k < 6; k++) red[wid][k] = acc6[k];
    }
    __syncthreads();
    if (t < 6) gpart[(long)blockIdx.x*6 + t] = red[0][t] + red[1][t] + red[2][t] + red[3][t];
}

// -------------------- K5: final reduction + scalar --------------------
__global__ __launch_bounds__(1024) void k_final(const float* __restrict__ gpart, int nb,
                                                const float* __restrict__ dense_b,
                                                float* __restrict__ out)
{
    const int t = threadIdx.x, lane = t & 63, wid = t >> 6;
    float acc[6] = {0.f,0.f,0.f,0.f,0.f,0.f};
    for (long i = t; i < nb; i += 1024) {
        #pragma unroll
        for (int k = 0; k < 6; k++) acc[k] += gpart[i*6 + k];
    }
    __shared__ float red[16][6];
    #pragma unroll
    for (int k = 0; k < 6; k++) {
        float v = acc[k];
        #pragma unroll
        for (int o = 32; o > 0; o >>= 1) v += __shfl_xor(v, o);
        if (lane == 0) red[wid][k] = v;
    }
    __syncthreads();
    if (t == 0) {
        float tot[6] = {0.f,0.f,0.f,0.f,0.f,0.f};
        #pragma unroll
        for (int w = 0; w < 16; w++)
            #pragma unroll
            for (int k = 0; k < 6; k++) tot[k] += red[w][k];
        float o = dense_b[0];
        #pragma unroll
        for (int h = 0; h < HEADS; h++) o += tot[3 + h] / tot[h];
        out[0] = o;
    }
}

extern "C" void kernel_launch(void* const* d_in, const int* in_sizes, int n_in,
                              void* d_out, int out_size, void* d_ws, size_t ws_size,
                              hipStream_t stream)
{
    const float* nf      = (const float*)d_in[0];
    const float* W_int   = (const float*)d_in[1];
    const float* as_int  = (const float*)d_in[2];
    const float* ad_int  = (const float*)d_in[3];
    const float* W_nh    = (const float*)d_in[4];
    const float* as_nh   = (const float*)d_in[5];
    const float* ad_nh   = (const float*)d_in[6];
    const float* att_w   = (const float*)d_in[7];
    const float* dense_w = (const float*)d_in[8];
    const float* dense_b = (const float*)d_in[9];
    const int*   e_int   = (const int*)d_in[10];
    const int*   e_nh    = (const int*)d_in[11];

    const int N  = in_sizes[0] / VF;
    const int E0 = in_sizes[10] / 2;
    const int E1 = in_sizes[11] / 2;
    const int nbin = (N + 255) >> 8;          // <= NBINMAX for N <= 131072

    float* ws = (float*)d_ws;
    const long Nl = N;

    uint* h0 = (uint*)ws;                      // 32N dwords (128B-padded rows)
    uint* h1 = (uint*)(ws + 32*Nl);
    float* es0 = ws + 64*Nl;
    float4* ed0 = (float4*)(ws + 68*Nl);
    float* es1 = ws + 72*Nl;
    float4* ed1 = (float4*)(ws + 76*Nl);
    int2* ms0 = (int2*)(ws + 80*Nl);
    int2* ms1 = (int2*)(ws + 82*Nl);
    int* binfill = (int*)(ws + 84*Nl);         // 2*NBINMAX
    uint* pk0 = (uint*)(binfill + 2*NBINMAX);  // nbin*CAP0
    uint* pk1 = pk0 + (long)nbin*CAP0;         // nbin*CAP1
    int* bk0  = (int*)(pk1 + (long)nbin*CAP1); // nbin*CAP0
    int* bk1  = bk0 + (long)nbin*CAP0;         // nbin*CAP1
    float* gpart = (float*)(bk1 + (long)nbin*CAP1);
    float* pd    = (float*)pk0;                // pk0 dead after k_binbucket; 6N <= nbin*CAP0

    const int nbK1 = (N + 63) / 64;
    const int nbs0 = (E0 + SCCH - 1) / SCCH;
    const int nbs1 = (E1 + SCCH - 1) / SCCH;

    k_nodes<<<nbK1, 256, 0, stream>>>(nf, W_int, as_int, ad_int, W_nh, as_nh, ad_nh,
                                      ws, binfill, N);
    k_binscatter<<<nbs0 + nbs1, 256, 0, stream>>>(e_int, E0, nbs0, e_nh, E1,
                                                  binfill, pk0, pk1);
    k_binbucket<<<2*nbin, 256, 0, stream>>>(pk0, pk1, binfill, nbin,
                                            ms0, bk0, ms1, bk1, N);
    k_gp<<<NBGP, 256, 0, stream>>>(h0, h1, es0, ed0, es1, ed1,
                                   ms0, bk0, ms1, bk1,
                                   att_w, dense_w, pd, gpart, N);
    k_final<<<1, 1024, 0, stream>>>(gpart, NBGP, dense_b, (float*)d_out);
}

// Round 14
// 144.872 us; speedup vs baseline: 1.3026x; 1.3026x over previous
//
#include <hip/hip_runtime.h>
#include <math.h>

#define HEADS 3
#define FILT 16
#define HF 48   // HEADS*FILT
#define VF 11

#define NBGP 2048          // k_gp blocks (x4 waves = 8192 waves)
#define NBINMAX 512        // bins of 256 dst each; N<=131072
#define CAP0 4096          // slack per bin, branch 0 (E0=400K, mean ~1k/bin)
#define CAP1 8192          // slack per bin, branch 1 (E1=1.6M, mean ~4k/bin)
#define SCCH 4096          // edges per k_binscatter block (more blocks = more TLP)

typedef unsigned int uint;
typedef unsigned short ushort;

__device__ inline uint f2bf(float x) {        // RNE f32->bf16 bits
    uint u = __float_as_uint(x);
    return (u + 0x7FFFu + ((u >> 16) & 1u)) >> 16;
}

__device__ inline float tanh_fast(float s) {
    const float sc = fminf(fmaxf(s, -15.f), 15.f);
    const float t = __expf(2.f * sc);
    return (t - 1.f) / (t + 1.f);
}

// ws layout (floats), Nl = N, nbin=(N+255)>>8:
//   h0 bf16[pad 128B rows] @0 (32N)   h1 @32N (32N)
//   es0[4N]@64N ed0[4N]@68N es1[4N]@72N ed1[4N]@76N
//   ms0 int2[N] @80N   ms1 int2[N] @82N     (cnt, bucket-end)
//   binfill[2*NBINMAX] @84N                  (ints)
//   pk0[nbin*CAP0] pk1[nbin*CAP1] bk0[nbin*CAP0] bk1[nbin*CAP1] after
//   gpart[NBGP*6] after

// -------------------- K1: per-node transform + init --------------------
// 4 threads per node (q = t&3 owns feats [12q,12q+12)). 64 nodes per block.
// H rows staged in LDS, written back block-coalesced (full-line writes).
__global__ __launch_bounds__(256) void k_nodes(
    const float* __restrict__ nf,
    const float* __restrict__ W_int, const float* __restrict__ as_int, const float* __restrict__ ad_int,
    const float* __restrict__ W_nh,  const float* __restrict__ as_nh,  const float* __restrict__ ad_nh,
    float* __restrict__ ws, int* __restrict__ binfill, int N)
{
    __shared__ float sW0[VF*HF], sW1[VF*HF];
    __shared__ float sa[4][HF];
    __shared__ float sF[64*VF];
    __shared__ uint  sH[64*32];
    const int t = threadIdx.x;
    for (int i = t; i < VF*HF; i += 256) { sW0[i] = W_int[i]; sW1[i] = W_nh[i]; }
    if (t < HF) { sa[0][t] = as_int[t]; sa[1][t] = ad_int[t]; sa[2][t] = as_nh[t]; sa[3][t] = ad_nh[t]; }

    const long Nl = N;
    const long B0 = (long)blockIdx.x * 64;
    {
        const long idx = (long)blockIdx.x * 256 + t;
        if (idx < 2*NBINMAX) binfill[idx] = 0;
    }
    // stage node features (coalesced)
    for (int i = t; i < 64*VF; i += 256) {
        const long g = B0*VF + i;
        sF[i] = (g < Nl*VF) ? nf[g] : 0.f;
    }
    __syncthreads();

    const int nl = t >> 2;       // local node 0..63
    const int q  = t & 3;        // feature quarter
    const long n = B0 + nl;
    const bool valid = n < Nl;

    float f[VF];
    #pragma unroll
    for (int v = 0; v < VF; v++) f[v] = sF[nl*VF + v];

    for (int b = 0; b < 2; b++) {
        if (b == 1) __syncthreads();   // protect sH reuse
        const float* W = b ? sW1 : sW0;
        float acc[12];
        #pragma unroll
        for (int j = 0; j < 12; j++) acc[j] = 0.f;
        #pragma unroll
        for (int v = 0; v < VF; v++) {
            const float fv = f[v];
            #pragma unroll
            for (int j = 0; j < 12; j++)
                acc[j] = fmaf(fv, W[v*HF + q*12 + j], acc[j]);
        }
        // stage bf16 pairs (6 dwords) + this thread's share of the pad
        #pragma unroll
        for (int i = 0; i < 6; i++)
            sH[nl*32 + q*6 + i] = f2bf(acc[2*i]) | (f2bf(acc[2*i+1]) << 16);
        sH[nl*32 + 24 + 2*q + 0] = 0u;
        sH[nl*32 + 24 + 2*q + 1] = 0u;

        // partial head-dots over this thread's 12 feats (predicated by head)
        float s0=0.f,s1=0.f,s2=0.f,d0=0.f,d1=0.f,d2=0.f;
        #pragma unroll
        for (int j = 0; j < 12; j++) {
            const int fg = q*12 + j;
            const int hd = fg >> 4;
            const float ps = acc[j] * sa[2*b + 0][fg];
            const float pd = acc[j] * sa[2*b + 1][fg];
            s0 += (hd == 0) ? ps : 0.f;  d0 += (hd == 0) ? pd : 0.f;
            s1 += (hd == 1) ? ps : 0.f;  d1 += (hd == 1) ? pd : 0.f;
            s2 += (hd == 2) ? ps : 0.f;  d2 += (hd == 2) ? pd : 0.f;
        }
        s0 += __shfl_xor(s0,1); s0 += __shfl_xor(s0,2);
        s1 += __shfl_xor(s1,1); s1 += __shfl_xor(s1,2);
        s2 += __shfl_xor(s2,1); s2 += __shfl_xor(s2,2);
        d0 += __shfl_xor(d0,1); d0 += __shfl_xor(d0,2);
        d1 += __shfl_xor(d1,1); d1 += __shfl_xor(d1,2);
        d2 += __shfl_xor(d2,1); d2 += __shfl_xor(d2,2);
        if (valid && q == 0) {
            float* ES = ws + 64*Nl + (b ? 8*Nl : 0);
            float* ED = ES + 4*Nl;
            ((float4*)ES)[n] = make_float4(s0, s1, s2, 0.f);
            ((float4*)ED)[n] = make_float4(d0, d1, d2, 0.f);
        }
        __syncthreads();
        // coalesced H write: 2048 dwords per block, 4 full lines per instr
        uint* Hg = (uint*)(ws + (b ? 32*Nl : 0));
        for (int i = t; i < 64*32; i += 256) {
            const long node = B0 + (i >> 5);
            if (node < Nl) Hg[B0*32 + i] = sH[i];
        }
    }
}

// -------------------- K2: multi-split edges into slack bins --------------------
__global__ __launch_bounds__(256) void k_binscatter(
    const int* __restrict__ e0, int E0, int nb0,
    const int* __restrict__ e1, int E1,
    int* __restrict__ binfill, uint* __restrict__ pk0, uint* __restrict__ pk1)
{
    __shared__ int lh[NBINMAX], lb[NBINMAX];
    const int b = blockIdx.x;
    const int* e; long E; int* bf; uint* pk; int bb, cap;
    if (b < nb0) { e = e0; E = E0; bf = binfill;           pk = pk0; bb = b;       cap = CAP0; }
    else         { e = e1; E = E1; bf = binfill + NBINMAX; pk = pk1; bb = b - nb0; cap = CAP1; }
    for (int i = threadIdx.x; i < NBINMAX; i += 256) lh[i] = 0;
    __syncthreads();
    const int t = threadIdx.x;
    const long base = (long)bb * SCCH;
    // phase 1: count
    #pragma unroll 4
    for (int k = 0; k < SCCH/256; k++) {
        const long i = base + (long)k*256 + t;
        if (i < E) atomicAdd(&lh[e[E + i] >> 8], 1);
    }
    __syncthreads();
    // phase 2: reserve slack space per bin; reset local counters
    for (int i = t; i < NBINMAX; i += 256) {
        const int c = lh[i];
        lb[i] = c ? atomicAdd(&bf[i], c) : 0;
        lh[i] = 0;
    }
    __syncthreads();
    // phase 3: scatter packed (dstl<<17 | src)
    #pragma unroll 4
    for (int k = 0; k < SCCH/256; k++) {
        const long i = base + (long)k*256 + t;
        if (i < E) {
            const int s = e[i];
            const int d = e[E + i];
            const int bin = d >> 8;
            const int off = atomicAdd(&lh[bin], 1);
            pk[(long)bin*cap + lb[bin] + off] = ((uint)(d & 255) << 17) | (uint)s;
        }
    }
}

// -------------------- K3: per-bin bucket build (4-way replicated LDS hist) -----
__global__ __launch_bounds__(256) void k_binbucket(
    const uint* __restrict__ pk0, const uint* __restrict__ pk1,
    const int* __restrict__ binfill, int nbin,
    int2* __restrict__ ms0, int* __restrict__ bk0,
    int2* __restrict__ ms1, int* __restrict__ bk1, int N)
{
    __shared__ int nc[4][256], wsum[4];
    const int b = blockIdx.x;
    const int br = (b < nbin) ? 0 : 1;
    const int bin = b - br*nbin;
    const uint* pk = br ? pk1 : pk0;
    const int cap  = br ? CAP1 : CAP0;
    int2* ms = br ? ms1 : ms0;
    int* bk  = br ? bk1 : bk0;
    const long pbase = (long)bin * cap;
    const int m = binfill[br*NBINMAX + bin];
    const int t = threadIdx.x, lane = t & 63, wid = t >> 6;

    #pragma unroll
    for (int r = 0; r < 4; r++) nc[r][t] = 0;
    __syncthreads();
    // pass 1: per-wave replica histogram (conflicts only intra-wave)
    for (int i = t; i < m; i += 256)
        atomicAdd(&nc[wid][(pk[pbase + i] >> 17) & 255], 1);
    __syncthreads();
    const int v = nc[0][t] + nc[1][t] + nc[2][t] + nc[3][t];
    // exclusive scan of v over 256 threads
    int x = v;
    #pragma unroll
    for (int d = 1; d < 64; d <<= 1) { const int u = __shfl_up(x, d); if (lane >= d) x += u; }
    if (lane == 63) wsum[wid] = x;
    __syncthreads();
    int wb = 0;
    #pragma unroll
    for (int w = 0; w < 4; w++) if (w < wid) wb += wsum[w];
    const int myexcl = wb + x - v;           // exclusive start for dst t
    const int n = bin*256 + t;
    if (n < N) ms[n] = make_int2(v, (int)pbase + myexcl + v);   // (cnt, bucket END)
    // convert nc to absolute per-replica cursors
    {
        int s = myexcl;
        #pragma unroll
        for (int r = 0; r < 4; r++) { const int c = nc[r][t]; nc[r][t] = s; s += c; }
    }
    __syncthreads();
    // pass 2: scatter via per-wave cursor
    for (int i = t; i < m; i += 256) {
        const uint p = pk[pbase + i];
        const int dl = (p >> 17) & 255;
        const int off = atomicAdd(&nc[wid][dl], 1);
        bk[pbase + off] = (int)(p & 0x1FFFFu);
    }
}

// -------------------- K4: gather-reduce + fused pooling --------------------
// 4 independent task chains per iteration (2 nodes x 2 branches) interleaved
// for memory-level parallelism. Fast path requires all degs <= 64 (Poisson
// lambda<=16 -> essentially always); slow path handles the rest.
// iw[] holds src*32 (H dword offset) to save a shift per gather.
__global__ __launch_bounds__(256) void k_gp(
    const uint* __restrict__ H0, const uint* __restrict__ H1,
    const float* __restrict__ ES0, const float4* __restrict__ ED0,
    const float* __restrict__ ES1, const float4* __restrict__ ED1,
    const int2* __restrict__ ms0, const int* __restrict__ bk0,
    const int2* __restrict__ ms1, const int* __restrict__ bk1,
    const float* __restrict__ att_w, const float* __restrict__ dense_w,
    float* __restrict__ gpart, int N)
{
    __shared__ int   sIdx[4][4*64];
    __shared__ float sP[4][4*192];
    const int t = threadIdx.x, lane = t & 63, wid = t >> 6;
    const int half = lane >> 5;          // 0: edge j, 1: edge j+1
    const int hl = lane & 31;            // dword within 128B row
    const int hcc = (hl >> 3) < 3 ? (hl >> 3) : 2;

    // pooling coefficients: half 0 -> score dots, half 1 -> dense dots
    float cL0[3]={0,0,0}, cH0[3]={0,0,0}, cL1[3]={0,0,0}, cH1[3]={0,0,0};
    if (hl < 24) {
        const int f0 = 2*hl, f1 = f0 + 1;
        #pragma unroll
        for (int k = 0; k < 3; k++) {
            if (half == 0) {
                cL0[k] = att_w[f0*3 + k];        cH0[k] = att_w[f1*3 + k];
                cL1[k] = att_w[(HF+f0)*3 + k];   cH1[k] = att_w[(HF+f1)*3 + k];
            } else {
                cL0[k] = dense_w[k*96 + f0];     cH0[k] = dense_w[k*96 + f1];
                cL1[k] = dense_w[k*96 + HF+f0];  cH1[k] = dense_w[k*96 + HF+f1];
            }
        }
    }

    int* iw = sIdx[wid];
    float* pw = sP[wid];

    float acc6[6] = {0,0,0,0,0,0};
    const int gw = blockIdx.x*4 + wid;
    const int nw = NBGP*4;

    for (int n = gw; n < N; n += 2*nw) {
        const int nB = n + nw;
        const bool hasB = nB < N;
        // task T: node = (T>>1)?nB:n, branch = T&1
        const int2 m0t = ms0[n];
        const int2 m1t = ms1[n];
        const int2 m2t = hasB ? ms0[nB] : make_int2(0, 0);
        const int2 m3t = hasB ? ms1[nB] : make_int2(0, 0);
        int deg[4] = {m0t.x, m1t.x, m2t.x, m3t.x};
        int bas[4] = {m0t.y - m0t.x, m1t.y - m1t.x, m2t.y - m2t.x, m3t.y - m3t.x};
        const int mx = max(max(deg[0], deg[1]), max(deg[2], deg[3]));

        float xL[4], xH[4];

        if (mx <= 64) {
            // ---- phase A, all 4 tasks interleaved ----
            float4 ev[4];
            ev[0] = ED0[n]; ev[1] = ED1[n];
            ev[2] = hasB ? ED0[nB] : make_float4(0,0,0,0);
            ev[3] = hasB ? ED1[nB] : make_float4(0,0,0,0);
            int sv[4];
            sv[0] = (lane < deg[0]) ? bk0[bas[0] + lane] : 0;
            sv[1] = (lane < deg[1]) ? bk1[bas[1] + lane] : 0;
            sv[2] = (lane < deg[2]) ? bk0[bas[2] + lane] : 0;
            sv[3] = (lane < deg[3]) ? bk1[bas[3] + lane] : 0;
            float4 es[4];
            es[0] = ((const float4*)ES0)[sv[0]];
            es[1] = ((const float4*)ES1)[sv[1]];
            es[2] = ((const float4*)ES0)[sv[2]];
            es[3] = ((const float4*)ES1)[sv[3]];
            #pragma unroll
            for (int T = 0; T < 4; T++) {
                float v0 = es[T].x + ev[T].x, v1 = es[T].y + ev[T].y, v2 = es[T].z + ev[T].z;
                v0 = fmaxf(v0, 0.2f*v0);
                v1 = fmaxf(v1, 0.2f*v1);
                v2 = fmaxf(v2, 0.2f*v2);
                const bool a = lane < deg[T];
                const float p0 = a ? __expf(v0) : 0.f;
                const float p1 = a ? __expf(v1) : 0.f;
                const float p2 = a ? __expf(v2) : 0.f;
                iw[T*64 + lane] = sv[T] << 5;          // dword offset of H row
                pw[T*192 + lane*3 + 0] = p0;
                pw[T*192 + lane*3 + 1] = p1;
                pw[T*192 + lane*3 + 2] = p2;
            }
            // ---- phase B: rounds of 8 edges, 4 tasks' loads issued together ----
            float accL[4] = {0,0,0,0}, accH[4] = {0,0,0,0}, den[4] = {0,0,0,0};
            const int R = (mx + 7) >> 3;
            for (int r = 0; r < R; r++) {
                const int j0 = r*8;
                uint w[4][4]; float q[4][4];
                #pragma unroll
                for (int T = 0; T < 4; T++) {
                    const uint* H = (T & 1) ? H1 : H0;
                    if (j0 < deg[T]) {
                        #pragma unroll
                        for (int u = 0; u < 4; u++) {
                            const int ei = j0 + 2*u + half;
                            q[T][u] = pw[T*192 + ei*3 + hcc];
                            w[T][u] = H[(long)iw[T*64 + ei] + hl];
                        }
                    }
                }
                #pragma unroll
                for (int T = 0; T < 4; T++) {
                    if (j0 < deg[T]) {
                        #pragma unroll
                        for (int u = 0; u < 4; u++) {
                            accL[T] = fmaf(q[T][u], __uint_as_float(w[T][u] << 16), accL[T]);
                            accH[T] = fmaf(q[T][u], __uint_as_float(w[T][u] & 0xFFFF0000u), accH[T]);
                            den[T] += q[T][u];
                        }
                    }
                }
            }
            #pragma unroll
            for (int T = 0; T < 4; T++) {
                accL[T] += __shfl_xor(accL[T], 32);
                accH[T] += __shfl_xor(accH[T], 32);
                den[T]  += __shfl_xor(den[T], 32);
                const float dinv = 1.f / (den[T] + 1e-16f);
                xL[T] = accL[T] * dinv;
                xH[T] = accH[T] * dinv;
            }
        } else {
            // ---- slow path (deg > 64 somewhere): old chunked structure ----
            #pragma unroll
            for (int T = 0; T < 4; T++) {
                const uint* H   = (T & 1) ? H1 : H0;
                const float* ES = (T & 1) ? ES1 : ES0;
                const float4* ED = (T & 1) ? ED1 : ED0;
                const int* bk   = (T & 1) ? bk1 : bk0;
                const int nn    = (T >> 1) ? nB : n;
                float accL = 0.f, accH = 0.f, dn = 0.f;
                if (deg[T] > 0) {
                    const float4 edv = ED[nn];
                    for (int e0 = 0; e0 < deg[T]; e0 += 64) {
                        int m = deg[T] - e0; if (m > 64) m = 64;
                        int srcv = 0; float p0 = 0.f, p1 = 0.f, p2 = 0.f;
                        if (lane < m) {
                            srcv = bk[bas[T] + e0 + lane];
                            const float4 esv = ((const float4*)ES)[srcv];
                            float v0 = esv.x + edv.x, v1 = esv.y + edv.y, v2 = esv.z + edv.z;
                            v0 = fmaxf(v0, 0.2f*v0);
                            v1 = fmaxf(v1, 0.2f*v1);
                            v2 = fmaxf(v2, 0.2f*v2);
                            p0 = __expf(v0); p1 = __expf(v1); p2 = __expf(v2);
                        }
                        iw[lane] = srcv << 5;
                        pw[lane*3 + 0] = p0; pw[lane*3 + 1] = p1; pw[lane*3 + 2] = p2;
                        for (int j = 0; j < m; j += 2) {
                            const int ei = j + half;
                            const float qq = pw[ei*3 + hcc];
                            const uint wv = H[(long)iw[ei] + hl];
                            accL = fmaf(qq, __uint_as_float(wv << 16), accL);
                            accH = fmaf(qq, __uint_as_float(wv & 0xFFFF0000u), accH);
                            dn += qq;
                        }
                    }
                }
                accL += __shfl_xor(accL, 32);
                accH += __shfl_xor(accH, 32);
                dn   += __shfl_xor(dn, 32);
                const float dinv = 1.f / (dn + 1e-16f);
                xL[T] = accL * dinv;
                xH[T] = accH * dinv;
            }
        }

        // ---- fused pooling per node (s=0: tasks 0,1; s=1: tasks 2,3) ----
        #pragma unroll
        for (int s = 0; s < 2; s++) {
            if (s == 1 && !hasB) break;
            float rr[3];
            #pragma unroll
            for (int k = 0; k < 3; k++)
                rr[k] = xL[2*s]*cL0[k] + xH[2*s]*cH0[k] + xL[2*s+1]*cL1[k] + xH[2*s+1]*cH1[k];
            #pragma unroll
            for (int k = 0; k < 3; k++) {
                #pragma unroll
                for (int o = 1; o < 32; o <<= 1) rr[k] += __shfl_xor(rr[k], o);
            }
            float oo[3];
            #pragma unroll
            for (int k = 0; k < 3; k++) oo[k] = __shfl_xor(rr[k], 32);
            if (lane == 0) {     // rr = scores, oo = dense dots (lane 0 is half 0)
                #pragma unroll
                for (int k = 0; k < 3; k++) {
                    const float e = __expf(tanh_fast(rr[k]));
                    acc6[k]   += e;
                    acc6[3+k] += e * oo[k];
                }
            }
        }
    }

    __shared__ float red[4][6];
    if (lane == 0) {
        #pragma unroll
        for (int k = 0; k < 6; k++) red[wid][k] = acc6[k];
    }
    __syncthreads();
    if (t < 6) gpart[(long)blockIdx.x*6 + t] = red[0][t] + red[1][t] + red[2][t] + red[3][t];
}

// -------------------- K5: final reduction + scalar --------------------
__global__ __launch_bounds__(1024) void k_final(const float* __restrict__ gpart, int nb,
                                                const float* __restrict__ dense_b,
                                                float* __restrict__ out)
{
    const int t = threadIdx.x, lane = t & 63, wid = t >> 6;
    float acc[6] = {0.f,0.f,0.f,0.f,0.f,0.f};
    for (long i = t; i < nb; i += 1024) {
        #pragma unroll
        for (int k = 0; k < 6; k++) acc[k] += gpart[i*6 + k];
    }
    __shared__ float red[16][6];
    #pragma unroll
    for (int k = 0; k < 6; k++) {
        float v = acc[k];
        #pragma unroll
        for (int o = 32; o > 0; o >>= 1) v += __shfl_xor(v, o);
        if (lane == 0) red[wid][k] = v;
    }
    __syncthreads();
    if (t == 0) {
        float tot[6] = {0.f,0.f,0.f,0.f,0.f,0.f};
        #pragma unroll
        for (int w = 0; w < 16; w++)
            #pragma unroll
            for (int k = 0; k < 6; k++) tot[k] += red[w][k];
        float o = dense_b[0];
        #pragma unroll
        for (int h = 0; h < HEADS; h++) o += tot[3 + h] / tot[h];
        out[0] = o;
    }
}

extern "C" void kernel_launch(void* const* d_in, const int* in_sizes, int n_in,
                              void* d_out, int out_size, void* d_ws, size_t ws_size,
                              hipStream_t stream)
{
    const float* nf      = (const float*)d_in[0];
    const float* W_int   = (const float*)d_in[1];
    const float* as_int  = (const float*)d_in[2];
    const float* ad_int  = (const float*)d_in[3];
    const float* W_nh    = (const float*)d_in[4];
    const float* as_nh   = (const float*)d_in[5];
    const float* ad_nh   = (const float*)d_in[6];
    const float* att_w   = (const float*)d_in[7];
    const float* dense_w = (const float*)d_in[8];
    const float* dense_b = (const float*)d_in[9];
    const int*   e_int   = (const int*)d_in[10];
    const int*   e_nh    = (const int*)d_in[11];

    const int N  = in_sizes[0] / VF;
    const int E0 = in_sizes[10] / 2;
    const int E1 = in_sizes[11] / 2;
    const int nbin = (N + 255) >> 8;          // <= NBINMAX for N <= 131072

    float* ws = (float*)d_ws;
    const long Nl = N;

    uint* h0 = (uint*)ws;                      // 32N dwords (128B-padded rows)
    uint* h1 = (uint*)(ws + 32*Nl);
    float* es0 = ws + 64*Nl;
    float4* ed0 = (float4*)(ws + 68*Nl);
    float* es1 = ws + 72*Nl;
    float4* ed1 = (float4*)(ws + 76*Nl);
    int2* ms0 = (int2*)(ws + 80*Nl);
    int2* ms1 = (int2*)(ws + 82*Nl);
    int* binfill = (int*)(ws + 84*Nl);         // 2*NBINMAX
    uint* pk0 = (uint*)(binfill + 2*NBINMAX);  // nbin*CAP0
    uint* pk1 = pk0 + (long)nbin*CAP0;         // nbin*CAP1
    int* bk0  = (int*)(pk1 + (long)nbin*CAP1); // nbin*CAP0
    int* bk1  = bk0 + (long)nbin*CAP0;         // nbin*CAP1
    float* gpart = (float*)(bk1 + (long)nbin*CAP1);

    const int nbK1 = (N + 63) / 64;
    const int nbs0 = (E0 + SCCH - 1) / SCCH;
    const int nbs1 = (E1 + SCCH - 1) / SCCH;

    k_nodes<<<nbK1, 256, 0, stream>>>(nf, W_int, as_int, ad_int, W_nh, as_nh, ad_nh,
                                      ws, binfill, N);
    k_binscatter<<<nbs0 + nbs1, 256, 0, stream>>>(e_int, E0, nbs0, e_nh, E1,
                                                  binfill, pk0, pk1);
    k_binbucket<<<2*nbin, 256, 0, stream>>>(pk0, pk1, binfill, nbin,
                                            ms0, bk0, ms1, bk1, N);
    k_gp<<<NBGP, 256, 0, stream>>>(h0, h1, es0, ed0, es1, ed1,
                                   ms0, bk0, ms1, bk1,
                                   att_w, dense_w, gpart, N);
    k_final<<<1, 1024, 0, stream>>>(gpart, NBGP, dense_b, (float*)d_out);
}